// Round 2
// baseline (319.724 us; speedup 1.0000x reference)
//
#include <hip/hip_runtime.h>
#include <hip/hip_fp16.h>

namespace {
constexpr int NN = 100000;   // nodes
constexpr int NE = 1600000;  // edges
constexpr int NF = 128;      // input feats
constexpr int NC = 40;       // classes (propagated dim after algebraic reorder)
constexpr int HP = 64;       // padded h row: 64 halfs = 128 B = exactly 1 L2 line
constexpr int BN = 128;      // nodes per bucket (halved: width > per-block depth)
constexpr int NBK = (NN + BN - 1) / BN;   // buckets = 782
constexpr int EPB = 4096;                 // edges per bucket-block
constexpr int EBK = (NE + EPB - 1) / EPB; // bucket blocks = 391
constexpr int CAP = 3072;                 // bucket capacity (mean 2048, sd 45 -> 22 sigma)
constexpr float FIX = 1048576.0f;         // 2^20 fixed-point scale for deg
constexpr int NPB = 51;                   // nodes per hop block (51*5 = 255 threads)
constexpr int HB  = (NN + NPB - 1) / NPB; // hop blocks = 1961
constexpr int TS  = 2048;                 // staged pairs per tile (16 KB LDS)
}

struct alignas(16) H8 { __half2 a, b, c, d; };   // 8 halfs = one b128

__device__ inline __half2 f2h2(float x, float y) {
    return __halves2half2(__float2half_rn(x), __float2half_rn(y));
}

// ---------------------------------------------------------------------------
// K1: coarse bucket sort of edges by col>>7 (782 bins of 128 nodes).
// LDS histogram pass 1 RETURNS each edge's in-bin rank (stored u8) so pass 2
// needs NO atomics. One returning device atomic per (block, touched-bin)
// (~300K total vs 1.6M in the naive design). Staged record packs
// {row:17, col&127:7} + w (8B).
__global__ __launch_bounds__(256) void k_bucket(const int* __restrict__ col,
                                                const int* __restrict__ row,
                                                const float* __restrict__ w,
                                                unsigned int* __restrict__ cursor,
                                                int2* __restrict__ bstage) {
    __shared__ unsigned int lhist[NBK];
    __shared__ unsigned int lbase[NBK];
    __shared__ unsigned char rk8[EPB];   // in-bin rank per staged edge
    int t = threadIdx.x;
    for (int i = t; i < NBK; i += 256) lhist[i] = 0u;
    __syncthreads();
    int e0 = blockIdx.x * EPB;
    int e1 = min(e0 + EPB, NE);
    for (int e = e0 + t; e < e1; e += 256) {
        unsigned r = atomicAdd(&lhist[col[e] >> 7], 1u);
        rk8[e - e0] = (unsigned char)r;      // per-block bin count max ~25
    }
    __syncthreads();
    for (int i = t; i < NBK; i += 256) {
        unsigned c = lhist[i];
        lbase[i] = c ? atomicAdd(&cursor[i], c) : 0u;   // ~300K device atomics total
    }
    __syncthreads();
    for (int e = e0 + t; e < e1; e += 256) {
        int c = col[e];                  // L1-hot re-read
        int b = c >> 7;
        int2 v;
        v.x = (row[e] & 0x1FFFF) | ((c & 127) << 17);
        v.y = __float_as_int(w[e]);
        bstage[(size_t)b * CAP + lbase[b] + rk8[e - e0]] = v;
    }
}

// K2: exclusive scan of 782 bucket counts -> bbase[0..NBK]; offs[NN] = NE.
__global__ __launch_bounds__(1024) void k_bscan(const unsigned int* __restrict__ cursor,
                                                int* __restrict__ bbase,
                                                int* __restrict__ offs) {
    __shared__ int s[1024];
    int t = threadIdx.x;
    int v = (t < NBK) ? (int)cursor[t] : 0;
    s[t] = v;
    __syncthreads();
    for (int off = 1; off < 1024; off <<= 1) {
        int add = (t >= off) ? s[t - off] : 0;
        __syncthreads();
        s[t] += add;
        __syncthreads();
    }
    if (t < NBK) bbase[t] = s[t] - v;          // exclusive
    if (t == NBK) bbase[NBK] = s[NBK - 1];     // total = NE
    if (t == 0)  offs[NN] = NE;
}

// K3: per-bucket (128 nodes, 782 blocks) counting sort by col&127 -> final
// CSR pair[], deg/dis via ONE returning u64 LDS atomic per edge (rank comes
// back for free -> stored u8, so the pair-write pass has NO atomics), then
// the XW GEMM for the same 128 nodes with a 2-thread/node CLASS SPLIT
// (acc[20] each -> low VGPR; upper classes exchanged through LDS that
// overlays the dead sort scratch):
//   z0[n] = fp16(dis[n] * (x[n] @ W))        (single fp16 rounding, as before)
// pair.y = w * dis[c]^2 ; final hop multiplies by invdis = sqrt(deg).
__global__ __launch_bounds__(256) void k_sortgemm(const int2* __restrict__ bstage,
                                                  const int* __restrict__ bbase,
                                                  const float* __restrict__ x,
                                                  const float* __restrict__ W,
                                                  int* __restrict__ offs,
                                                  float* __restrict__ invdis,
                                                  int2* __restrict__ pair,
                                                  __half* __restrict__ z0) {
    // overlay: sort phase {lpk u64[BN] | lr8 u8[CAP]} then GEMM fx[BN][20]
    __shared__ char sbuf[BN * 20 * 4];        // 10240 B >= 1024 + 3072
    unsigned long long* lpk = (unsigned long long*)sbuf;
    unsigned char* lr8 = (unsigned char*)(sbuf + BN * 8);
    float (*fx)[20] = (float (*)[20])sbuf;
    __shared__ int ls[BN];
    __shared__ float ldis[BN];
    int t = threadIdx.x;
    int b = blockIdx.x;
    int base = bbase[b];
    int cnt  = bbase[b + 1] - base;
    if (t < BN) lpk[t] = 0ull;
    __syncthreads();
    const int2* bs = bstage + (size_t)b * CAP;
    for (int j = t; j < cnt; j += 256) {
        int2 s = bs[j];
        int cl = (s.x >> 17) & 127;
        unsigned long long q =
            (unsigned long long)(unsigned)(__int_as_float(s.y) * FIX + 0.5f);
        unsigned long long old = atomicAdd(&lpk[cl], (1ull << 40) | q);
        lr8[j] = (unsigned char)(old >> 40);  // in-bin rank (max in-deg ~45)
    }
    __syncthreads();
    int myc = 0;
    float dis = 0.f, deg = 0.f;
    if (t < BN) {
        myc = (int)(lpk[t] >> 40);
        deg = (float)(lpk[t] & ((1ull << 40) - 1)) * (1.0f / FIX);
        dis = (deg > 0.f) ? rsqrtf(deg) : 0.f;
        ldis[t] = dis;
        ls[t] = myc;
    }
    __syncthreads();
    for (int off = 1; off < BN; off <<= 1) {
        int add = (t >= off && t < BN) ? ls[t - off] : 0;
        __syncthreads();
        if (t < BN) ls[t] += add;
        __syncthreads();
    }
    int n0 = b * BN + t;                      // node for t < BN
    if (t < BN) {
        ls[t] -= myc;                         // exclusive start within bucket
        if (n0 < NN) {
            offs[n0] = base + ls[t];
            invdis[n0] = sqrtf(fmaxf(deg, 0.f));   // = 1/dis (0 when deg==0)
        }
    }
    __syncthreads();
    for (int j = t; j < cnt; j += 256) {
        int2 s = bs[j];                       // L2-hot re-read
        int cl = (s.x >> 17) & 127;
        float d = ldis[cl];
        int2 v;
        v.x = s.x & 0x1FFFF;
        v.y = __float_as_int(__int_as_float(s.y) * d * d);   // w * dis[c]^2
        pair[base + ls[cl] + lr8[j]] = v;     // semi-coalesced, atomic-free
    }
    __syncthreads();   // lr8 dead; sbuf becomes fx[][]
    // ---- GEMM phase: 128 nodes, 2 threads/node (class halves) ----
    int nl = t & (BN - 1);
    int jh = t >> 7;                          // wave-uniform (waves 0,1 vs 2,3)
    int n = b * BN + nl;
    float acc[20];
#pragma unroll
    for (int j = 0; j < 20; ++j) acc[j] = 0.f;
    if (n < NN) {
        const float4* xr = (const float4*)(x + (size_t)n * NF);  // 32 float4
        const float4* W4 = (const float4*)W + jh * 5;            // class offset 20
        for (int k4 = 0; k4 < NF / 4; ++k4) {
            float4 xv = xr[k4];
#pragma unroll
            for (int kk = 0; kk < 4; ++kk) {
                float xk = (kk == 0) ? xv.x : (kk == 1) ? xv.y : (kk == 2) ? xv.z : xv.w;
                int k = k4 * 4 + kk;
#pragma unroll
                for (int j4 = 0; j4 < 5; ++j4) {
                    float4 wv = W4[k * 10 + j4];   // wave-uniform address
                    acc[j4 * 4 + 0] += xk * wv.x;
                    acc[j4 * 4 + 1] += xk * wv.y;
                    acc[j4 * 4 + 2] += xk * wv.z;
                    acc[j4 * 4 + 3] += xk * wv.w;
                }
            }
        }
    }
    if (jh == 1 && n < NN) {
#pragma unroll
        for (int j = 0; j < 20; ++j) fx[nl][j] = acc[j];
    }
    __syncthreads();
    if (jh == 0 && n < NN) {
        float sc = ldis[nl];                  // fold dis into z0 (one fp16 round)
        const float* hi = fx[nl];
        H8* o = (H8*)(z0 + (size_t)n * HP);
        H8 v;
        v.a = f2h2(acc[0] * sc, acc[1] * sc);
        v.b = f2h2(acc[2] * sc, acc[3] * sc);
        v.c = f2h2(acc[4] * sc, acc[5] * sc);
        v.d = f2h2(acc[6] * sc, acc[7] * sc);
        o[0] = v;
        v.a = f2h2(acc[8] * sc, acc[9] * sc);
        v.b = f2h2(acc[10] * sc, acc[11] * sc);
        v.c = f2h2(acc[12] * sc, acc[13] * sc);
        v.d = f2h2(acc[14] * sc, acc[15] * sc);
        o[1] = v;
        v.a = f2h2(acc[16] * sc, acc[17] * sc);
        v.b = f2h2(acc[18] * sc, acc[19] * sc);
        v.c = f2h2(hi[0] * sc, hi[1] * sc);
        v.d = f2h2(hi[2] * sc, hi[3] * sc);
        o[2] = v;
        v.a = f2h2(hi[4] * sc, hi[5] * sc);
        v.b = f2h2(hi[6] * sc, hi[7] * sc);
        v.c = f2h2(hi[8] * sc, hi[9] * sc);
        v.d = f2h2(hi[10] * sc, hi[11] * sc);
        o[3] = v;
        v.a = f2h2(hi[12] * sc, hi[13] * sc);
        v.b = f2h2(hi[14] * sc, hi[15] * sc);
        v.c = f2h2(hi[16] * sc, hi[17] * sc);
        v.d = f2h2(hi[18] * sc, hi[19] * sc);
        o[4] = v;
    }
}

// LDS-staged pull hop. Block = 51 nodes x 5 threads (255 active). Offsets are
// absolute. pair.y = w*dis[c]^2, so hops 1..2 need no scaling; the FINAL hop
// multiplies by invdis[n] (h3 = D A z2). Gather loop unrolled 4-wide.
template <bool FINAL>
__global__ __launch_bounds__(256) void k_hop(const int* __restrict__ offs,
                                             const int2* __restrict__ pair,
                                             const __half* __restrict__ hin,
                                             __half* __restrict__ houth,
                                             float* __restrict__ houtf,
                                             const float* __restrict__ invdis) {
    __shared__ int2 tile[TS];
    __shared__ int erange[2];
    int t = threadIdx.x;
    int g = t / 5;                      // local node 0..50
    int n = blockIdx.x * NPB + g;
    bool active = (t < NPB * 5) && (n < NN);
    int vo = (t - g * 5) * 8;           // half offset 0,8,16,24,32
    int s0 = 0, s1 = 0;
    if (active) {
        s0 = offs[n];
        s1 = offs[n + 1];               // offs[NN] = NE
    }
    if (t == 0) {
        int n0 = blockIdx.x * NPB;
        int nl = min(n0 + NPB, NN);
        erange[0] = offs[n0];
        erange[1] = offs[nl];
    }
    __syncthreads();
    int E0 = erange[0], E1 = erange[1];
    float acc[8];
#pragma unroll
    for (int j = 0; j < 8; ++j) acc[j] = 0.f;
    int i = s0;
#define ACC8(m, wgt) { float2 f_;                                        \
    f_ = __half22float2((m).a); acc[0] += f_.x * (wgt); acc[1] += f_.y * (wgt); \
    f_ = __half22float2((m).b); acc[2] += f_.x * (wgt); acc[3] += f_.y * (wgt); \
    f_ = __half22float2((m).c); acc[4] += f_.x * (wgt); acc[5] += f_.y * (wgt); \
    f_ = __half22float2((m).d); acc[6] += f_.x * (wgt); acc[7] += f_.y * (wgt); }
    for (int t0 = E0; t0 < E1; t0 += TS) {
        int lim = min(t0 + TS, E1);
        int cnt = lim - t0;
        for (int j = t; j < cnt; j += 256) tile[j] = pair[t0 + j];  // coalesced
        __syncthreads();
        if (active) {
            int hi = min(s1, lim);
            for (; i + 4 <= hi; i += 4) {
                int2 p0 = tile[i - t0];
                int2 p1 = tile[i + 1 - t0];
                int2 p2 = tile[i + 2 - t0];
                int2 p3 = tile[i + 3 - t0];
                H8 m0 = *(const H8*)(hin + (size_t)p0.x * HP + vo);
                H8 m1 = *(const H8*)(hin + (size_t)p1.x * HP + vo);
                H8 m2 = *(const H8*)(hin + (size_t)p2.x * HP + vo);
                H8 m3 = *(const H8*)(hin + (size_t)p3.x * HP + vo);
                float w0 = __int_as_float(p0.y);
                float w1 = __int_as_float(p1.y);
                float w2 = __int_as_float(p2.y);
                float w3 = __int_as_float(p3.y);
                ACC8(m0, w0) ACC8(m1, w1) ACC8(m2, w2) ACC8(m3, w3)
            }
            for (; i < hi; ++i) {
                int2 p0 = tile[i - t0];
                H8 m0 = *(const H8*)(hin + (size_t)p0.x * HP + vo);
                float w0 = __int_as_float(p0.y);
                ACC8(m0, w0)
            }
        }
        __syncthreads();
    }
#undef ACC8
    if (active) {
        if (FINAL) {
            float sc = invdis[n];
            float* o = houtf + (size_t)n * NC + vo;
            float4 v0 = {acc[0] * sc, acc[1] * sc, acc[2] * sc, acc[3] * sc};
            float4 v1 = {acc[4] * sc, acc[5] * sc, acc[6] * sc, acc[7] * sc};
            *(float4*)(o) = v0;
            *(float4*)(o + 4) = v1;
        } else {
            H8 v;
            v.a = f2h2(acc[0], acc[1]);
            v.b = f2h2(acc[2], acc[3]);
            v.c = f2h2(acc[4], acc[5]);
            v.d = f2h2(acc[6], acc[7]);
            *(H8*)(houth + (size_t)n * HP + vo) = v;
        }
    }
}

extern "C" void kernel_launch(void* const* d_in, const int* in_sizes, int n_in,
                              void* d_out, int out_size, void* d_ws, size_t ws_size,
                              hipStream_t stream) {
    const float* x  = (const float*)d_in[0];
    const int*   ei = (const int*)d_in[1];   // [2, NE]
    const float* w  = (const float*)d_in[2];
    const float* W  = (const float*)d_in[3]; // [128, 40]
    const int* row = ei;
    const int* col = ei + NE;
    float* out = (float*)d_out;              // [NN, NC] fp32, written by hop3 only

    // workspace (~45.6 MB):
    //   [0, 19.2)   bstage  (dead after k_sortgemm)  -- hb OVERLAYS [0, 12.8)
    //   [19.2,32.0) ha  (z0 / z2, fp16)
    //   [32.0,44.8) pair {row, w*dis^2}
    //   then offs[NN+1], bbase[NBK+1], invdis[NN], cursor[NBK]
    char* base = (char*)d_ws;
    int2* bstage = (int2*)base;
    __half* hb   = (__half*)base;                         // born at hop1
    char* p = base + (size_t)NBK * CAP * 8;
    __half* ha = (__half*)p;        p += (size_t)NN * HP * 2;
    int2* pair = (int2*)p;          p += (size_t)NE * 8;
    int*  offs = (int*)p;           p += (size_t)(NN + 1) * 4;
    int*  bbase = (int*)p;          p += (size_t)(NBK + 1) * 4;
    float* invdis = (float*)p;      p += (size_t)NN * 4;
    unsigned int* cursor = (unsigned int*)p;

    hipMemsetAsync(cursor, 0, (size_t)NBK * 4, stream);
    k_bucket<<<EBK, 256, 0, stream>>>(col, row, w, cursor, bstage);
    k_bscan<<<1, 1024, 0, stream>>>(cursor, bbase, offs);
    k_sortgemm<<<NBK, 256, 0, stream>>>(bstage, bbase, x, W, offs, invdis, pair, ha);

    k_hop<false><<<HB, 256, 0, stream>>>(offs, pair, ha, hb, nullptr, nullptr);  // z1
    k_hop<false><<<HB, 256, 0, stream>>>(offs, pair, hb, ha, nullptr, nullptr);  // z2
    k_hop<true ><<<HB, 256, 0, stream>>>(offs, pair, ha, nullptr, out, invdis);  // h3
}

// Round 4
// 264.151 us; speedup vs baseline: 1.2104x; 1.2104x over previous
//
#include <hip/hip_runtime.h>
#include <hip/hip_fp16.h>

namespace {
constexpr int NN = 100000;   // nodes
constexpr int NE = 1600000;  // edges
constexpr int NF = 128;      // input feats
constexpr int NC = 40;       // classes (propagated dim after algebraic reorder)
constexpr int HP = 64;       // padded h row: 64 halfs = 128 B = exactly 1 L2 line
constexpr int NB = (NN + 255) / 256;      // node buckets (256 nodes each) = 391
constexpr int EPB = 4096;                 // edges per bucket-block
constexpr int EBK = (NE + EPB - 1) / EPB; // bucket blocks = 391
constexpr int CAP = 6144;                 // bucket capacity (mean 4096, sd 64 -> >16 sigma)
constexpr float FIX = 1048576.0f;         // 2^20 fixed-point scale for deg
constexpr int NPB = 51;                   // nodes per hop block (51*5 = 255 threads)
constexpr int HB  = (NN + NPB - 1) / NPB; // hop blocks = 1961
constexpr int TS  = 2048;                 // staged pairs per tile (16 KB LDS)
}

struct alignas(16) H8 { __half2 a, b, c, d; };   // 8 halfs = one b128

__device__ inline __half2 f2h2(float x, float y) {
    return __halves2half2(__float2half_rn(x), __float2half_rn(y));
}

// ---------------------------------------------------------------------------
// K1: coarse bucket sort of edges by col>>8 (391 bins of 256 nodes).
// LDS histogram + one returning device atomic per (block, bin) (~153K total),
// LDS ranks in pass 2. Staged record packs {row:17, col&255:8} + w (8B).
__global__ __launch_bounds__(256) void k_bucket(const int* __restrict__ col,
                                                const int* __restrict__ row,
                                                const float* __restrict__ w,
                                                unsigned int* __restrict__ cursor,
                                                int2* __restrict__ bstage) {
    __shared__ unsigned int lhist[NB];
    __shared__ unsigned int lbase[NB];
    __shared__ unsigned int lrank[NB];
    int t = threadIdx.x;
    for (int i = t; i < NB; i += 256) { lhist[i] = 0u; lrank[i] = 0u; }
    __syncthreads();
    int e0 = blockIdx.x * EPB;
    int e1 = min(e0 + EPB, NE);
    for (int e = e0 + t; e < e1; e += 256)
        atomicAdd(&lhist[col[e] >> 8], 1u);
    __syncthreads();
    for (int i = t; i < NB; i += 256) {
        unsigned c = lhist[i];
        lbase[i] = c ? atomicAdd(&cursor[i], c) : 0u;
    }
    __syncthreads();
    for (int e = e0 + t; e < e1; e += 256) {
        int c = col[e];                  // L1-hot re-read
        int b = c >> 8;
        unsigned r = atomicAdd(&lrank[b], 1u);
        int2 v;
        v.x = (row[e] & 0x1FFFF) | ((c & 255) << 17);
        v.y = __float_as_int(w[e]);
        bstage[(size_t)b * CAP + lbase[b] + r] = v;
    }
}

// K2: exclusive scan of 391 bucket counts -> bbase[0..NB]; offs[NN] = NE.
__global__ __launch_bounds__(512) void k_bscan(const unsigned int* __restrict__ cursor,
                                               int* __restrict__ bbase,
                                               int* __restrict__ offs) {
    __shared__ int s[512];
    int t = threadIdx.x;
    int v = (t < NB) ? (int)cursor[t] : 0;
    s[t] = v;
    __syncthreads();
    for (int off = 1; off < 512; off <<= 1) {
        int add = (t >= off) ? s[t - off] : 0;
        __syncthreads();
        s[t] += add;
        __syncthreads();
    }
    if (t < NB) bbase[t] = s[t] - v;          // exclusive
    if (t == NB) bbase[NB] = s[NB - 1];       // total = NE
    if (t == 0)  offs[NN] = NE;
}

// K3: per-bucket (256 nodes) counting sort by col&255 -> final CSR pair[],
// deg/dis via ONE u64 LDS atomic per edge, per-node offs/invdis, then the
// XW GEMM for the same 256 nodes with dis folded into the fp16 output:
//   z0[n] = fp16(dis[n] * (x[n] @ W))        (single fp16 rounding)
// pair.y = w * dis[c]^2 ; final hop multiplies by invdis = sqrt(deg).
// W staged in LDS (20 KB): the GEMM previously issued 1280 wave-uniform
// global float4 W-loads per thread through the TA pipe at ~1.5 blocks/CU —
// the latency-bound cost behind VALUBusy 9% / occ 16%. Staging loads issue
// before the sort passes, so their latency hides completely.
// [round-3 post-mortem: crashed on lW[NF*NC/16]=320 (should be /4=1280) —
//  15 KB LDS overrun. Fixed here; design otherwise identical.]
__global__ __launch_bounds__(256) void k_sortgemm(const int2* __restrict__ bstage,
                                                  const int* __restrict__ bbase,
                                                  const float* __restrict__ x,
                                                  const float* __restrict__ W,
                                                  int* __restrict__ offs,
                                                  float* __restrict__ invdis,
                                                  int2* __restrict__ pair,
                                                  __half* __restrict__ z0) {
    __shared__ unsigned long long lpk[256];   // [63:40]=cnt, [39:0]=deg fixed-point
    __shared__ int ls[256];                   // counts -> scan -> starts
    __shared__ float ldis[256];
    __shared__ unsigned int lrank[256];
    __shared__ float4 lW[NF * NC / 4];        // 1280 float4 = 20 KB, row k = 10 float4
    int t = threadIdx.x;
    int b = blockIdx.x;
    int base = bbase[b];
    int cnt  = bbase[b + 1] - base;
    {   // stage W early: 5 coalesced float4 loads/thread, latency hidden by sort
        const float4* Wg = (const float4*)W;
#pragma unroll
        for (int i = 0; i < 5; ++i) lW[t + i * 256] = Wg[t + i * 256];
    }
    lpk[t] = 0ull;
    lrank[t] = 0u;
    __syncthreads();
    const int2* bs = bstage + (size_t)b * CAP;
    for (int j = t; j < cnt; j += 256) {
        int2 s = bs[j];
        int cl = (s.x >> 17) & 255;
        unsigned long long q =
            (unsigned long long)(unsigned)(__int_as_float(s.y) * FIX + 0.5f);
        atomicAdd(&lpk[cl], (1ull << 40) | q);
    }
    __syncthreads();
    int myc = (int)(lpk[t] >> 40);
    float deg = (float)(lpk[t] & ((1ull << 40) - 1)) * (1.0f / FIX);
    float dis = (deg > 0.f) ? rsqrtf(deg) : 0.f;
    ldis[t] = dis;
    ls[t] = myc;
    __syncthreads();
    for (int off = 1; off < 256; off <<= 1) {
        int add = (t >= off) ? ls[t - off] : 0;
        __syncthreads();
        ls[t] += add;
        __syncthreads();
    }
    int start = ls[t] - myc;                  // exclusive within bucket
    int n = b * 256 + t;
    if (n < NN) {
        offs[n] = base + start;
        invdis[n] = sqrtf(fmaxf(deg, 0.f));   // = 1/dis (0 when deg==0)
    }
    ls[t] = start;
    __syncthreads();
    for (int j = t; j < cnt; j += 256) {
        int2 s = bs[j];                       // L2-hot re-read
        int cl = (s.x >> 17) & 255;
        unsigned r = atomicAdd(&lrank[cl], 1u);
        float d = ldis[cl];
        int2 v;
        v.x = s.x & 0x1FFFF;
        v.y = __float_as_int(__int_as_float(s.y) * d * d);   // w * dis[c]^2
        pair[base + ls[cl] + r] = v;          // semi-coalesced (block-local range)
    }
    // ---- GEMM phase: this block owns exactly nodes [b*256, b*256+256) ----
    if (n < NN) {
        const float4* xr = (const float4*)(x + (size_t)n * NF);  // 32 float4
        float acc[NC];
#pragma unroll
        for (int j = 0; j < NC; ++j) acc[j] = 0.f;
        for (int k4 = 0; k4 < NF / 4; ++k4) {
            float4 xv = xr[k4];
#pragma unroll
            for (int kk = 0; kk < 4; ++kk) {
                float xk = (kk == 0) ? xv.x : (kk == 1) ? xv.y : (kk == 2) ? xv.z : xv.w;
                int k = k4 * 4 + kk;
#pragma unroll
                for (int j4 = 0; j4 < 10; ++j4) {
                    float4 wv = lW[k * 10 + j4];   // LDS broadcast (was global VMEM)
                    acc[j4 * 4 + 0] += xk * wv.x;
                    acc[j4 * 4 + 1] += xk * wv.y;
                    acc[j4 * 4 + 2] += xk * wv.z;
                    acc[j4 * 4 + 3] += xk * wv.w;
                }
            }
        }
        float sc = ldis[t];                   // fold dis into z0 (one fp16 round)
        H8* o = (H8*)(z0 + (size_t)n * HP);
#pragma unroll
        for (int g = 0; g < 5; ++g) {         // 5 x 8 halfs = 40
            H8 v;
            v.a = f2h2(acc[g * 8 + 0] * sc, acc[g * 8 + 1] * sc);
            v.b = f2h2(acc[g * 8 + 2] * sc, acc[g * 8 + 3] * sc);
            v.c = f2h2(acc[g * 8 + 4] * sc, acc[g * 8 + 5] * sc);
            v.d = f2h2(acc[g * 8 + 6] * sc, acc[g * 8 + 7] * sc);
            o[g] = v;
        }
    }
}

// LDS-staged pull hop. Block = 51 nodes x 5 threads (255 active). Offsets are
// absolute. pair.y = w*dis[c]^2, so hops 1..2 need no scaling; the FINAL hop
// multiplies by invdis[n] (h3 = D A z2). Gather loop unrolled 4-wide.
template <bool FINAL>
__global__ __launch_bounds__(256) void k_hop(const int* __restrict__ offs,
                                             const int2* __restrict__ pair,
                                             const __half* __restrict__ hin,
                                             __half* __restrict__ houth,
                                             float* __restrict__ houtf,
                                             const float* __restrict__ invdis) {
    __shared__ int2 tile[TS];
    __shared__ int erange[2];
    int t = threadIdx.x;
    int g = t / 5;                      // local node 0..50
    int n = blockIdx.x * NPB + g;
    bool active = (t < NPB * 5) && (n < NN);
    int vo = (t - g * 5) * 8;           // half offset 0,8,16,24,32
    int s0 = 0, s1 = 0;
    if (active) {
        s0 = offs[n];
        s1 = offs[n + 1];               // offs[NN] = NE
    }
    if (t == 0) {
        int n0 = blockIdx.x * NPB;
        int nl = min(n0 + NPB, NN);
        erange[0] = offs[n0];
        erange[1] = offs[nl];
    }
    __syncthreads();
    int E0 = erange[0], E1 = erange[1];
    float acc[8];
#pragma unroll
    for (int j = 0; j < 8; ++j) acc[j] = 0.f;
    int i = s0;
#define ACC8(m, wgt) { float2 f_;                                        \
    f_ = __half22float2((m).a); acc[0] += f_.x * (wgt); acc[1] += f_.y * (wgt); \
    f_ = __half22float2((m).b); acc[2] += f_.x * (wgt); acc[3] += f_.y * (wgt); \
    f_ = __half22float2((m).c); acc[4] += f_.x * (wgt); acc[5] += f_.y * (wgt); \
    f_ = __half22float2((m).d); acc[6] += f_.x * (wgt); acc[7] += f_.y * (wgt); }
    for (int t0 = E0; t0 < E1; t0 += TS) {
        int lim = min(t0 + TS, E1);
        int cnt = lim - t0;
        for (int j = t; j < cnt; j += 256) tile[j] = pair[t0 + j];  // coalesced
        __syncthreads();
        if (active) {
            int hi = min(s1, lim);
            for (; i + 4 <= hi; i += 4) {
                int2 p0 = tile[i - t0];
                int2 p1 = tile[i + 1 - t0];
                int2 p2 = tile[i + 2 - t0];
                int2 p3 = tile[i + 3 - t0];
                H8 m0 = *(const H8*)(hin + (size_t)p0.x * HP + vo);
                H8 m1 = *(const H8*)(hin + (size_t)p1.x * HP + vo);
                H8 m2 = *(const H8*)(hin + (size_t)p2.x * HP + vo);
                H8 m3 = *(const H8*)(hin + (size_t)p3.x * HP + vo);
                float w0 = __int_as_float(p0.y);
                float w1 = __int_as_float(p1.y);
                float w2 = __int_as_float(p2.y);
                float w3 = __int_as_float(p3.y);
                ACC8(m0, w0) ACC8(m1, w1) ACC8(m2, w2) ACC8(m3, w3)
            }
            for (; i < hi; ++i) {
                int2 p0 = tile[i - t0];
                H8 m0 = *(const H8*)(hin + (size_t)p0.x * HP + vo);
                float w0 = __int_as_float(p0.y);
                ACC8(m0, w0)
            }
        }
        __syncthreads();
    }
#undef ACC8
    if (active) {
        if (FINAL) {
            float sc = invdis[n];
            float* o = houtf + (size_t)n * NC + vo;
            float4 v0 = {acc[0] * sc, acc[1] * sc, acc[2] * sc, acc[3] * sc};
            float4 v1 = {acc[4] * sc, acc[5] * sc, acc[6] * sc, acc[7] * sc};
            *(float4*)(o) = v0;
            *(float4*)(o + 4) = v1;
        } else {
            H8 v;
            v.a = f2h2(acc[0], acc[1]);
            v.b = f2h2(acc[2], acc[3]);
            v.c = f2h2(acc[4], acc[5]);
            v.d = f2h2(acc[6], acc[7]);
            *(H8*)(houth + (size_t)n * HP + vo) = v;
        }
    }
}

extern "C" void kernel_launch(void* const* d_in, const int* in_sizes, int n_in,
                              void* d_out, int out_size, void* d_ws, size_t ws_size,
                              hipStream_t stream) {
    const float* x  = (const float*)d_in[0];
    const int*   ei = (const int*)d_in[1];   // [2, NE]
    const float* w  = (const float*)d_in[2];
    const float* W  = (const float*)d_in[3]; // [128, 40]
    const int* row = ei;
    const int* col = ei + NE;
    float* out = (float*)d_out;              // [NN, NC] fp32, written by hop3 only

    // workspace (~45.6 MB):
    //   [0, 19.2)   bstage  (dead after k_sortgemm)  -- hb OVERLAYS [0, 12.8)
    //   [19.2,32.0) ha  (z0 / z2, fp16)
    //   [32.0,44.8) pair {row, w*dis^2}
    //   then offs[NN+1], bbase[NB+1], invdis[NN], cursor[NB]
    char* base = (char*)d_ws;
    int2* bstage = (int2*)base;
    __half* hb   = (__half*)base;                         // born at hop1
    char* p = base + (size_t)NB * CAP * 8;
    __half* ha = (__half*)p;        p += (size_t)NN * HP * 2;
    int2* pair = (int2*)p;          p += (size_t)NE * 8;
    int*  offs = (int*)p;           p += (size_t)(NN + 1) * 4;
    int*  bbase = (int*)p;          p += (size_t)(NB + 1) * 4;
    float* invdis = (float*)p;      p += (size_t)NN * 4;
    unsigned int* cursor = (unsigned int*)p;

    hipMemsetAsync(cursor, 0, (size_t)NB * 4, stream);
    k_bucket<<<EBK, 256, 0, stream>>>(col, row, w, cursor, bstage);
    k_bscan<<<1, 512, 0, stream>>>(cursor, bbase, offs);
    k_sortgemm<<<NB, 256, 0, stream>>>(bstage, bbase, x, W, offs, invdis, pair, ha);

    k_hop<false><<<HB, 256, 0, stream>>>(offs, pair, ha, hb, nullptr, nullptr);  // z1
    k_hop<false><<<HB, 256, 0, stream>>>(offs, pair, hb, ha, nullptr, nullptr);  // z2
    k_hop<true ><<<HB, 256, 0, stream>>>(offs, pair, ha, nullptr, out, invdis);  // h3
}